// Round 4
// baseline (1674.470 us; speedup 1.0000x reference)
//
#include <hip/hip_runtime.h>
#include <math.h>

#define TPB 256
#define NPGC 64
#define EPGC 128
#define K1C 52
#define K2C 42
#define F0 30
#define F1 50
#define F2 100

struct SMem {
    union U1 {
        struct { float x[NPGC * F0]; float hW1[NPGC * F1]; float W1[F0 * F1]; } a;  // conv1
        struct { float hW2h[K1C * F1]; float W2h[F1 * F1]; } c;                     // conv2 (half)
        float h2p[K2C * F2];                                                         // pooled-2 feats
    } u1;
    union U2 {
        float h1[NPGC * F1];   // conv1 out
        float h2[K1C * F2];    // conv2 out
        struct { float pooled[200]; float muv[50]; float lemb[200]; float d1v[100]; float d2v[200]; } head;
    } u2;
    float h1p[K1C * F1];       // pool1 output feats
    int   row[EPGC];
    int   col[EPGC];
    float ew[EPGC];
    float nrm[EPGC];
    float deg[NPGC];           // holds deg then dinv
    float score[NPGC];
    int   map[NPGC];
    int   inv[NPGC];
    float pw[F2];
    float scal;
};

extern "C" __global__ __launch_bounds__(TPB)
void molgen_fused(const float* __restrict__ x,
                  const int* __restrict__ ei,
                  const int* __restrict__ smile_len,
                  const float* __restrict__ w1,  const float* __restrict__ b1,
                  const float* __restrict__ pw1,
                  const float* __restrict__ w2,  const float* __restrict__ b2,
                  const float* __restrict__ pw2,
                  const float* __restrict__ mean_w,   const float* __restrict__ mean_b,
                  const float* __restrict__ logvar_w, const float* __restrict__ logvar_b,
                  const float* __restrict__ emb,
                  const float* __restrict__ dec1_w, const float* __restrict__ dec1_b,
                  const float* __restrict__ dec2_w, const float* __restrict__ dec2_b,
                  const float* __restrict__ out_w,  const float* __restrict__ out_b,
                  float* __restrict__ out,
                  int B, int E)
{
    __shared__ SMem s;
    const int g = blockIdx.x;
    const int t = threadIdx.x;

    // ---------------- conv1 ----------------
    for (int o = t; o < NPGC * F0; o += TPB) s.u1.a.x[o] = x[(size_t)g * NPGC * F0 + o];
    for (int o = t; o < F0 * F1; o += TPB)   s.u1.a.W1[o] = w1[o];
    for (int e = t; e < EPGC; e += TPB) {
        s.row[e] = ei[(size_t)g * EPGC + e] - g * NPGC;
        s.col[e] = ei[(size_t)E + (size_t)g * EPGC + e] - g * NPGC;
    }
    if (t < NPGC) s.deg[t] = 1.0f;           // self-loop weight
    __syncthreads();

    for (int e = t; e < EPGC; e += TPB) atomicAdd(&s.deg[s.col[e]], 1.0f);
    for (int o = t; o < NPGC * F1; o += TPB) {   // hW1 = x @ W1
        int n = o / F1, f = o - n * F1;
        float acc = 0.f;
        #pragma unroll
        for (int i = 0; i < F0; ++i) acc += s.u1.a.x[n * F0 + i] * s.u1.a.W1[i * F1 + f];
        s.u1.a.hW1[o] = acc;
    }
    __syncthreads();
    if (t < NPGC) s.deg[t] = rsqrtf(s.deg[t]);   // dinv (deg >= 1 always)
    __syncthreads();
    for (int e = t; e < EPGC; e += TPB) s.nrm[e] = s.deg[s.row[e]] * s.deg[s.col[e]];
    for (int o = t; o < NPGC * F1; o += TPB) {   // init: bias + self-loop message
        int n = o / F1, f = o - n * F1;
        s.u2.h1[o] = b1[f] + s.u1.a.hW1[o] * s.deg[n] * s.deg[n];
    }
    __syncthreads();
    for (int p = t; p < EPGC * F1; p += TPB) {   // edge scatter
        int e = p / F1, f = p - e * F1;
        atomicAdd(&s.u2.h1[s.col[e] * F1 + f], s.u1.a.hW1[s.row[e] * F1 + f] * s.nrm[e]);
    }
    __syncthreads();
    for (int o = t; o < NPGC * F1; o += TPB) s.u2.h1[o] = fmaxf(s.u2.h1[o], 0.f);
    if (t < F1) s.pw[t] = pw1[t];
    __syncthreads();

    // ---------------- pool1 (top-52 of 64) ----------------
    if (t == 0) {
        float ss = 0.f;
        for (int i = 0; i < F1; ++i) ss += s.pw[i] * s.pw[i];
        s.scal = sqrtf(ss);
    }
    __syncthreads();
    if (t < NPGC) {
        float acc = 0.f;
        for (int i = 0; i < F1; ++i) acc += s.u2.h1[t * F1 + i] * s.pw[i];
        s.score[t] = tanhf(acc / s.scal);
    }
    __syncthreads();
    if (t < NPGC) {   // stable descending rank == jax.lax.top_k order
        float sc = s.score[t]; int r = 0;
        for (int m = 0; m < NPGC; ++m) {
            float sm = s.score[m];
            r += (sm > sc) || (sm == sc && m < t);
        }
        s.map[t] = (r < K1C) ? r : -1;
        if (r < K1C) s.inv[r] = t;
    }
    __syncthreads();
    for (int p = t; p < K1C * F1; p += TPB) {
        int r = p / F1, f = p - r * F1;
        int n = s.inv[r];
        s.h1p[p] = s.u2.h1[n * F1 + f] * s.score[n];
    }
    for (int e = t; e < EPGC; e += TPB) {   // remap edges
        int rl = s.map[s.row[e]], cl = s.map[s.col[e]];
        bool keep = (rl >= 0) && (cl >= 0);
        s.row[e] = keep ? rl : 0;
        s.col[e] = keep ? cl : 0;
        s.ew[e]  = keep ? 1.f : 0.f;
    }
    if (t < K1C) s.deg[t] = 1.0f;
    __syncthreads();

    // ---------------- conv2 ----------------
    for (int e = t; e < EPGC; e += TPB) if (s.ew[e] != 0.f) atomicAdd(&s.deg[s.col[e]], 1.0f);
    __syncthreads();
    if (t < K1C) s.deg[t] = rsqrtf(s.deg[t]);
    __syncthreads();
    for (int e = t; e < EPGC; e += TPB) s.nrm[e] = s.deg[s.row[e]] * s.ew[e] * s.deg[s.col[e]];
    __syncthreads();

    for (int half = 0; half < 2; ++half) {
        for (int o = t; o < F1 * F1; o += TPB) {   // stage W2 column-half
            int i = o / F1, fh = o - i * F1;
            s.u1.c.W2h[o] = w2[i * F2 + half * F1 + fh];
        }
        __syncthreads();
        for (int o = t; o < K1C * F1; o += TPB) {  // hW2 half = h1p @ W2h
            int n = o / F1, fh = o - n * F1;
            float acc = 0.f;
            #pragma unroll 5
            for (int i = 0; i < F1; ++i) acc += s.h1p[n * F1 + i] * s.u1.c.W2h[i * F1 + fh];
            s.u1.c.hW2h[o] = acc;
        }
        __syncthreads();
        for (int o = t; o < K1C * F1; o += TPB) {  // init h2 half: bias + self-loop
            int n = o / F1, fh = o - n * F1;
            s.u2.h2[n * F2 + half * F1 + fh] = b2[half * F1 + fh] + s.u1.c.hW2h[o] * s.deg[n] * s.deg[n];
        }
        __syncthreads();
        for (int p = t; p < EPGC * F1; p += TPB) { // edge scatter half
            int e = p / F1, fh = p - e * F1;
            float nm = s.nrm[e];
            if (nm != 0.f)
                atomicAdd(&s.u2.h2[s.col[e] * F2 + half * F1 + fh],
                          s.u1.c.hW2h[s.row[e] * F1 + fh] * nm);
        }
        __syncthreads();
    }
    for (int o = t; o < K1C * F2; o += TPB) s.u2.h2[o] = fmaxf(s.u2.h2[o], 0.f);
    if (t < F2) s.pw[t] = pw2[t];
    __syncthreads();

    // ---------------- pool2 (top-42 of 52) ----------------
    if (t == 0) {
        float ss = 0.f;
        for (int i = 0; i < F2; ++i) ss += s.pw[i] * s.pw[i];
        s.scal = sqrtf(ss);
    }
    __syncthreads();
    if (t < K1C) {
        float acc = 0.f;
        for (int i = 0; i < F2; ++i) acc += s.u2.h2[t * F2 + i] * s.pw[i];
        s.score[t] = tanhf(acc / s.scal);
    }
    __syncthreads();
    if (t < K1C) {
        float sc = s.score[t]; int r = 0;
        for (int m = 0; m < K1C; ++m) {
            float sm = s.score[m];
            r += (sm > sc) || (sm == sc && m < t);
        }
        if (r < K2C) s.inv[r] = t;
    }
    __syncthreads();
    for (int p = t; p < K2C * F2; p += TPB) {
        int r = p / F2, f = p - r * F2;
        int n = s.inv[r];
        s.u1.h2p[p] = s.u2.h2[n * F2 + f] * s.score[n];
    }
    __syncthreads();   // u2.h2 dead from here; u2.head aliases it

    // ---------------- readout ----------------
    if (t < F2) {
        float mx = -INFINITY, sm = 0.f;
        for (int r = 0; r < K2C; ++r) {
            float v = s.u1.h2p[r * F2 + t];
            mx = fmaxf(mx, v);
            sm += v;
        }
        s.u2.head.pooled[t]      = mx;
        s.u2.head.pooled[F2 + t] = sm * (1.0f / (float)K2C);
    }
    const int sl = smile_len[g];
    __syncthreads();
    if (t < 200) s.u2.head.lemb[t] = fmaxf(emb[(size_t)sl * 200 + t], 0.f);
    __syncthreads();

    // ---------------- dense head ----------------
    if (t < 50) {                       // mu
        float acc = mean_b[t];
        for (int i = 0; i < 200; ++i) acc += s.u2.head.pooled[i] * mean_w[i * 50 + t];
        acc = fmaxf(acc, 0.f);
        s.u2.head.muv[t] = acc;
        out[(size_t)B * 200 + (size_t)g * 50 + t] = acc;
    } else if (t >= 64 && t < 114) {    // logvar
        int j = t - 64;
        float acc = logvar_b[j];
        for (int i = 0; i < 200; ++i) acc += s.u2.head.pooled[i] * logvar_w[i * 50 + j];
        acc = fmaxf(acc, 0.f);
        out[(size_t)B * 250 + (size_t)g * 50 + j] = acc;
    }
    __syncthreads();
    if (t < 100) {                      // d1 = relu([mu, lemb] @ dec1_w + b)
        float acc = dec1_b[t];
        for (int i = 0; i < 50; ++i)  acc += s.u2.head.muv[i]  * dec1_w[i * 100 + t];
        for (int i = 0; i < 200; ++i) acc += s.u2.head.lemb[i] * dec1_w[(50 + i) * 100 + t];
        s.u2.head.d1v[t] = fmaxf(acc, 0.f);
    }
    __syncthreads();
    if (t < 200) {                      // d2 = relu(d1 @ dec2_w + b) + lemb
        float acc = dec2_b[t];
        for (int i = 0; i < 100; ++i) acc += s.u2.head.d1v[i] * dec2_w[i * 200 + t];
        s.u2.head.d2v[t] = fmaxf(acc, 0.f) + s.u2.head.lemb[t];
    }
    __syncthreads();
    if (t < 200) {                      // out = relu(d2 @ out_w + b)
        float acc = out_b[t];
        for (int i = 0; i < 200; ++i) acc += s.u2.head.d2v[i] * out_w[i * 200 + t];
        out[(size_t)g * 200 + t] = fmaxf(acc, 0.f);
    }
}

extern "C" void kernel_launch(void* const* d_in, const int* in_sizes, int n_in,
                              void* d_out, int out_size, void* d_ws, size_t ws_size,
                              hipStream_t stream) {
    const float* x        = (const float*)d_in[0];
    const int*   ei       = (const int*)d_in[1];
    // d_in[2] = batch (unused: graphs are block-constant)
    const int*   slen     = (const int*)d_in[3];
    const float* w1       = (const float*)d_in[4];
    const float* b1       = (const float*)d_in[5];
    const float* pw1      = (const float*)d_in[6];
    const float* w2       = (const float*)d_in[7];
    const float* b2       = (const float*)d_in[8];
    const float* pw2      = (const float*)d_in[9];
    const float* mean_w   = (const float*)d_in[10];
    const float* mean_b   = (const float*)d_in[11];
    const float* logvar_w = (const float*)d_in[12];
    const float* logvar_b = (const float*)d_in[13];
    const float* emb      = (const float*)d_in[14];
    const float* dec1_w   = (const float*)d_in[15];
    const float* dec1_b   = (const float*)d_in[16];
    const float* dec2_w   = (const float*)d_in[17];
    const float* dec2_b   = (const float*)d_in[18];
    const float* out_w    = (const float*)d_in[19];
    const float* out_b    = (const float*)d_in[20];

    const int B = in_sizes[3];           // 8192 graphs
    const int E = in_sizes[1] / 2;       // directed edges total

    molgen_fused<<<B, TPB, 0, stream>>>(x, ei, slen, w1, b1, pw1, w2, b2, pw2,
                                        mean_w, mean_b, logvar_w, logvar_b, emb,
                                        dec1_w, dec1_b, dec2_w, dec2_b, out_w, out_b,
                                        (float*)d_out, B, E);
}

// Round 5
// 1272.036 us; speedup vs baseline: 1.3164x; 1.3164x over previous
//
#include <hip/hip_runtime.h>
#include <math.h>

#define TPB  256
#define NPGC 64
#define EPGC 128
#define K1C  52
#define K2C  42
#define F0   30
#define F1   50
#define F2   100

// ---------------- graph kernel: conv1 -> pool1 -> conv2 -> pool2 -> readout ----------------
// LDS plan (38.6 KB -> 4 blocks/CU):
//   big : hW1 [64][50] (conv1)  UNION  hW2 [52][101] (conv2, odd-padded)
//   h1  : [64][51] (odd-padded), lives conv1->conv2 (indirection replaces h1p)
//   CSR : per-col incoming edge lists, rebuilt for conv2 (deterministic, no atomics)
struct GS {
    float big[K1C * 101];        // 21008 B
    float h1[NPGC * 51];         // 13056 B
    int   rowm[EPGC];            // edge rows (remapped in place)
    int   colm[EPGC];            // edge cols; -1 == dropped (conv2)
    float nrm[EPGC];
    int   off[NPGC + 1];
    int   erow[EPGC];
    float enrm[EPGC];
    float dinv[NPGC];
    float score[NPGC];
    float score2[K1C];
    int   inv[NPGC];
    int   inv2[K1C];
    int   map[NPGC];
    int   cnt[NPGC];
};

__global__ __launch_bounds__(TPB, 4)
void molgen_graph(const float* __restrict__ x,
                  const int* __restrict__ ei,
                  const float* __restrict__ w1,  const float* __restrict__ b1,
                  const float* __restrict__ pw1,
                  const float* __restrict__ w2,  const float* __restrict__ cb2,
                  const float* __restrict__ pw2,
                  float* __restrict__ ws_pooled,
                  int E)
{
    __shared__ GS s;
    const int g = blockIdx.x;
    const int t = threadIdx.x;

    // P0: load edges (local indices)
    if (t < EPGC) {
        s.rowm[t] = ei[(size_t)g * EPGC + t] - g * NPGC;
        s.colm[t] = ei[(size_t)E + (size_t)g * EPGC + t] - g * NPGC;
    }
    __syncthreads();

    // P1: hW1 = x @ W1 (global x, global W1 -> L1 broadcast) ; cnt1 + dinv1
    for (int o = t; o < NPGC * F1; o += TPB) {
        int n = o / F1, f = o - n * F1;
        const float* xr = x + (size_t)g * (NPGC * F0) + n * F0;
        float a = 0.f;
        #pragma unroll
        for (int i = 0; i < F0; ++i) a += xr[i] * w1[i * F1 + f];
        s.big[o] = a;                       // hW1[n][f], stride 50
    }
    if (t < NPGC) {
        int c = 0;
        for (int e = 0; e < EPGC; ++e) c += (s.colm[e] == t);
        s.cnt[t] = c;
        s.dinv[t] = rsqrtf(1.0f + (float)c); // +1 self-loop
    }
    __syncthreads();

    // P2: prefix offsets (t0) ; nrm per edge
    if (t == 0) {
        s.off[0] = 0;
        for (int n = 0; n < NPGC; ++n) s.off[n + 1] = s.off[n] + s.cnt[n];
    }
    if (t < EPGC) s.nrm[t] = s.dinv[s.rowm[t]] * s.dinv[s.colm[t]];
    __syncthreads();

    // P3: deterministic CSR fill (slot = off[col] + #earlier edges with same col)
    if (t < EPGC) {
        int c = s.colm[t], r = 0;
        for (int e = 0; e < t; ++e) r += (s.colm[e] == c);
        int slot = s.off[c] + r;
        s.erow[slot] = s.rowm[t];
        s.enrm[slot] = s.nrm[t];
    }
    __syncthreads();

    // P4: h1 = relu(b1 + D^-1/2(A+I)D^-1/2 hW1)  (gather, no atomics)
    for (int o = t; o < NPGC * F1; o += TPB) {
        int n = o / F1, f = o - n * F1;
        float dn = s.dinv[n];
        float a = b1[f] + dn * dn * s.big[n * F1 + f];
        int e0 = s.off[n], e1 = s.off[n + 1];
        for (int j = e0; j < e1; ++j) a += s.enrm[j] * s.big[s.erow[j] * F1 + f];
        s.h1[n * 51 + f] = fmaxf(a, 0.f);
    }
    __syncthreads();

    // P5: pool1 scores (sequential dot, matches reference order)
    if (t < NPGC) {
        float ss = 0.f, a = 0.f;
        for (int i = 0; i < F1; ++i) { float w = pw1[i]; ss += w * w; a += s.h1[t * 51 + i] * w; }
        s.score[t] = tanhf(a / sqrtf(ss));
    }
    __syncthreads();

    // P6: stable descending rank (== jax.lax.top_k)
    if (t < NPGC) {
        float sc = s.score[t]; int r = 0;
        for (int m = 0; m < NPGC; ++m) {
            float sm = s.score[m];
            r += (sm > sc) || (sm == sc && m < t);
        }
        s.map[t] = (r < K1C) ? r : -1;
        if (r < K1C) s.inv[r] = t;
    }
    __syncthreads();

    // P7: remap edges (dropped -> col = -1)
    if (t < EPGC) {
        int rl = s.map[s.rowm[t]], cl = s.map[s.colm[t]];
        bool keep = (rl >= 0) && (cl >= 0);
        s.rowm[t] = rl;
        s.colm[t] = keep ? cl : -1;
    }
    __syncthreads();

    // P8: cnt2 + dinv2
    if (t < K1C) {
        int c = 0;
        for (int e = 0; e < EPGC; ++e) c += (s.colm[e] == t);
        s.cnt[t] = c;
        s.dinv[t] = rsqrtf(1.0f + (float)c);
    }
    __syncthreads();

    // P9: prefix ; nrm2
    if (t == 0) {
        s.off[0] = 0;
        for (int n = 0; n < K1C; ++n) s.off[n + 1] = s.off[n] + s.cnt[n];
    }
    if (t < EPGC) {
        int c = s.colm[t];
        s.nrm[t] = (c >= 0) ? s.dinv[s.rowm[t]] * s.dinv[c] : 0.f;
    }
    __syncthreads();

    // P10: CSR2 fill (t<128)  +  hW2 = (h1[inv]*score) @ W2 (all threads)
    if (t < EPGC) {
        int c = s.colm[t];
        if (c >= 0) {
            int r = 0;
            for (int e = 0; e < t; ++e) r += (s.colm[e] == c);
            int slot = s.off[c] + r;
            s.erow[slot] = s.rowm[t];
            s.enrm[slot] = s.nrm[t];
        }
    }
    for (int o = t; o < K1C * F2; o += TPB) {
        int n = o / F2, f = o - n * F2;
        int iv = s.inv[n];
        float sc = s.score[iv];
        const float* hr = &s.h1[iv * 51];
        float a = 0.f;
        #pragma unroll 5
        for (int i = 0; i < F1; ++i) a += hr[i] * w2[i * F2 + f];
        s.big[n * 101 + f] = a * sc;        // hW2[n][f], stride 101
    }
    __syncthreads();

    // P11: pool2 scores — h2 row recomputed on the fly (never stored)
    if (t < K1C) {
        float dn = s.dinv[t];
        int e0 = s.off[t], e1 = s.off[t + 1];
        float ss = 0.f, a = 0.f;
        for (int f = 0; f < F2; ++f) {
            float w = pw2[f]; ss += w * w;
            float v = cb2[f] + dn * dn * s.big[t * 101 + f];
            for (int j = e0; j < e1; ++j) v += s.enrm[j] * s.big[s.erow[j] * 101 + f];
            a += fmaxf(v, 0.f) * w;
        }
        s.score2[t] = tanhf(a / sqrtf(ss));
    }
    __syncthreads();

    // P12: rank2
    if (t < K1C) {
        float sc = s.score2[t]; int r = 0;
        for (int m = 0; m < K1C; ++m) {
            float sm = s.score2[m];
            r += (sm > sc) || (sm == sc && m < t);
        }
        if (r < K2C) s.inv2[r] = t;
    }
    __syncthreads();

    // P13: readout (max & mean over 42 selected recomputed h2 rows) -> ws
    if (t < F2) {
        float mx = -INFINITY, sm = 0.f;
        for (int r = 0; r < K2C; ++r) {
            int n = s.inv2[r];
            float dn = s.dinv[n], sc = s.score2[n];
            float v = cb2[t] + dn * dn * s.big[n * 101 + t];
            int e0 = s.off[n], e1 = s.off[n + 1];
            for (int j = e0; j < e1; ++j) v += s.enrm[j] * s.big[s.erow[j] * 101 + t];
            float y = fmaxf(v, 0.f) * sc;
            mx = fmaxf(mx, y);
            sm += y;
        }
        float* pd = ws_pooled + (size_t)g * 200;
        pd[t]       = mx;
        pd[F2 + t]  = sm * (1.0f / (float)K2C);
    }
}

// ---------------- head kernel: 16 graphs/block, dense chain ----------------
#define GPB 16
struct HS {
    union {
        float sp[GPB * 201];                                  // pooled staging
        struct { float d1[GPB * 100]; float d2[GPB * 201]; } b; // later phases
    } u;
    float le[GPB * 201];
    float muv[GPB * 50];
    int   sls[GPB];
};

__global__ __launch_bounds__(TPB, 4)
void molgen_head(const float* __restrict__ ws_pooled,
                 const int* __restrict__ smile_len,
                 const float* __restrict__ emb,
                 const float* __restrict__ mean_w,   const float* __restrict__ mean_b,
                 const float* __restrict__ logvar_w, const float* __restrict__ logvar_b,
                 const float* __restrict__ dec1_w, const float* __restrict__ dec1_b,
                 const float* __restrict__ dec2_w, const float* __restrict__ dec2_b,
                 const float* __restrict__ out_w,  const float* __restrict__ out_b,
                 float* __restrict__ out, int B)
{
    __shared__ HS h;
    const int t  = threadIdx.x;
    const int g0 = blockIdx.x * GPB;
    const int gc = min(GPB, B - g0);

    if (t < gc) h.sls[t] = smile_len[g0 + t];
    __syncthreads();
    for (int o = t; o < GPB * 200; o += TPB) {
        int gg = o / 200, f = o - gg * 200;
        if (gg < gc) {
            h.u.sp[gg * 201 + f] = ws_pooled[(size_t)(g0 + gg) * 200 + f];
            h.le[gg * 201 + f]   = fmaxf(emb[(size_t)h.sls[gg] * 200 + f], 0.f);
        }
    }
    __syncthreads();
    // mu (-> out chunk 1 and LDS) ; logvar (-> out chunk 2)
    for (int o = t; o < GPB * 50; o += TPB) {
        int gg = o / 50, j = o - gg * 50;
        if (gg < gc) {
            const float* sp = &h.u.sp[gg * 201];
            float a = mean_b[j];
            for (int i = 0; i < 200; ++i) a += sp[i] * mean_w[i * 50 + j];
            a = fmaxf(a, 0.f);
            h.muv[gg * 50 + j] = a;
            out[(size_t)B * 200 + (size_t)(g0 + gg) * 50 + j] = a;
        }
    }
    for (int o = t; o < GPB * 50; o += TPB) {
        int gg = o / 50, j = o - gg * 50;
        if (gg < gc) {
            const float* sp = &h.u.sp[gg * 201];
            float a = logvar_b[j];
            for (int i = 0; i < 200; ++i) a += sp[i] * logvar_w[i * 50 + j];
            out[(size_t)B * 250 + (size_t)(g0 + gg) * 50 + j] = fmaxf(a, 0.f);
        }
    }
    __syncthreads();   // sp dead; muv ready
    // d1 = relu([mu, lemb] @ dec1_w + b)
    for (int o = t; o < GPB * 100; o += TPB) {
        int gg = o / 100, j = o - gg * 100;
        const float* mv = &h.muv[gg * 50];
        const float* le = &h.le[gg * 201];
        float a = dec1_b[j];
        for (int i = 0; i < 50;  ++i) a += mv[i] * dec1_w[i * 100 + j];
        for (int i = 0; i < 200; ++i) a += le[i] * dec1_w[(50 + i) * 100 + j];
        h.u.b.d1[gg * 100 + j] = fmaxf(a, 0.f);
    }
    __syncthreads();
    // d2 = relu(d1 @ dec2_w + b) + lemb
    for (int o = t; o < GPB * 200; o += TPB) {
        int gg = o / 200, j = o - gg * 200;
        const float* d1 = &h.u.b.d1[gg * 100];
        float a = dec2_b[j];
        for (int i = 0; i < 100; ++i) a += d1[i] * dec2_w[i * 200 + j];
        h.u.b.d2[gg * 201 + j] = fmaxf(a, 0.f) + h.le[gg * 201 + j];
    }
    __syncthreads();
    // out = relu(d2 @ out_w + b)
    for (int o = t; o < GPB * 200; o += TPB) {
        int gg = o / 200, j = o - gg * 200;
        if (gg < gc) {
            const float* d2 = &h.u.b.d2[gg * 201];
            float a = out_b[j];
            for (int i = 0; i < 200; ++i) a += d2[i] * out_w[i * 200 + j];
            out[(size_t)(g0 + gg) * 200 + j] = fmaxf(a, 0.f);
        }
    }
}

extern "C" void kernel_launch(void* const* d_in, const int* in_sizes, int n_in,
                              void* d_out, int out_size, void* d_ws, size_t ws_size,
                              hipStream_t stream) {
    const float* x        = (const float*)d_in[0];
    const int*   ei       = (const int*)d_in[1];
    // d_in[2] = batch (unused: graphs are block-constant)
    const int*   slen     = (const int*)d_in[3];
    const float* w1       = (const float*)d_in[4];
    const float* b1       = (const float*)d_in[5];
    const float* pw1      = (const float*)d_in[6];
    const float* w2       = (const float*)d_in[7];
    const float* b2       = (const float*)d_in[8];
    const float* pw2      = (const float*)d_in[9];
    const float* mean_w   = (const float*)d_in[10];
    const float* mean_b   = (const float*)d_in[11];
    const float* logvar_w = (const float*)d_in[12];
    const float* logvar_b = (const float*)d_in[13];
    const float* emb      = (const float*)d_in[14];
    const float* dec1_w   = (const float*)d_in[15];
    const float* dec1_b   = (const float*)d_in[16];
    const float* dec2_w   = (const float*)d_in[17];
    const float* dec2_b   = (const float*)d_in[18];
    const float* out_w    = (const float*)d_in[19];
    const float* out_b    = (const float*)d_in[20];

    const int B = in_sizes[3];           // 8192 graphs
    const int E = in_sizes[1] / 2;       // directed edges total

    float* pooled = (float*)d_ws;        // [B][200] fp32 = 6.55 MB

    molgen_graph<<<B, TPB, 0, stream>>>(x, ei, w1, b1, pw1, w2, b2, pw2, pooled, E);
    molgen_head<<<(B + GPB - 1) / GPB, TPB, 0, stream>>>(pooled, slen, emb,
        mean_w, mean_b, logvar_w, logvar_b, dec1_w, dec1_b, dec2_w, dec2_b,
        out_w, out_b, (float*)d_out, B);
}

// Round 6
// 593.271 us; speedup vs baseline: 2.8224x; 2.1441x over previous
//
#include <hip/hip_runtime.h>
#include <math.h>

#define TPB  256
#define NPGC 64
#define EPGC 128
#define K1C  52
#define K2C  42
#define F0   30
#define F1   50
#define F2   100

// ---------------- graph kernel ----------------
// LDS ~37.8KB -> 4 blocks/CU.
struct GS {
    float big[K1C * 101];      // hW1 [64][50] (12800B of it), then hW2 [52][101]
    union {
        float xs[NPGC * F0];   // staged x (conv1)
        float h1[NPGC * 51];   // conv1 output (padded stride 51)
        float rd[400];         // readout partials [mx0,mx1,sm0,sm1][100]
    } u;
    int   rowm[EPGC];
    int   colm[EPGC];          // -1 == dropped (conv2)
    int   off[NPGC + 1];
    int   erow[EPGC];
    float enrm[EPGC];
    float dinv[NPGC];
    float score[NPGC];
    float score2[K1C];
    int   inv[NPGC];
    int   inv2[K2C];
    int   map[NPGC];
};

__global__ __launch_bounds__(TPB, 4)
void molgen_graph(const float* __restrict__ x,
                  const int* __restrict__ ei,
                  const float* __restrict__ w1,  const float* __restrict__ b1,
                  const float* __restrict__ pw1,
                  const float* __restrict__ w2,  const float* __restrict__ cb2,
                  const float* __restrict__ pw2,
                  float* __restrict__ ws_pooled,
                  int E)
{
    __shared__ GS s;
    const int g = blockIdx.x;
    const int t = threadIdx.x;

    // P0: edges + stage x
    if (t < EPGC) {
        s.rowm[t] = ei[(size_t)g * EPGC + t] - g * NPGC;
        s.colm[t] = ei[(size_t)E + (size_t)g * EPGC + t] - g * NPGC;
    }
    for (int o = t; o < NPGC * F0; o += TPB) s.u.xs[o] = x[(size_t)g * (NPGC * F0) + o];
    __syncthreads();

    // P1: hW1 = x @ W1, register-blocked 7 rows x 2 cols per thread (250 threads)
    if (t < 250) {
        const int fb = t % 25, nb = t / 25;
        const int f0 = fb * 2;
        float acc[7][2];
        #pragma unroll
        for (int r = 0; r < 7; ++r) { acc[r][0] = 0.f; acc[r][1] = 0.f; }
        for (int i = 0; i < F0; ++i) {
            const float2 w = *(const float2*)(w1 + i * F1 + f0);
            #pragma unroll
            for (int r = 0; r < 7; ++r) {
                const float h = s.u.xs[(nb + 10 * r) * F0 + i];  // in-struct even if n>=64
                acc[r][0] += h * w.x;
                acc[r][1] += h * w.y;
            }
        }
        #pragma unroll
        for (int r = 0; r < 7; ++r) {
            const int n = nb + 10 * r;
            if (n < NPGC) *(float2*)(&s.big[n * F1 + f0]) = make_float2(acc[r][0], acc[r][1]);
        }
    }
    __syncthreads();

    // P2: indegree (serial broadcast scan), dinv, wave-scan prefix -> off
    if (t < NPGC) {
        int c = 0;
        for (int e = 0; e < EPGC; ++e) c += (s.colm[e] == t);
        s.dinv[t] = rsqrtf(1.0f + (float)c);
        int sc_ = c;
        #pragma unroll
        for (int d = 1; d < 64; d <<= 1) {
            int y = __shfl_up(sc_, d, 64);
            if (t >= d) sc_ += y;
        }
        s.off[t + 1] = sc_;
        if (t == 0) s.off[0] = 0;
    }
    __syncthreads();

    // P3: deterministic CSR fill (stable within-column order)
    if (t < EPGC) {
        const int r_ = s.rowm[t], c_ = s.colm[t];
        const float nm = s.dinv[r_] * s.dinv[c_];
        int k = 0;
        for (int e = 0; e < t; ++e) k += (s.colm[e] == c_);
        const int slot = s.off[c_] + k;
        s.erow[slot] = r_;
        s.enrm[slot] = nm;
    }
    __syncthreads();

    // P4: h1 = relu(b1 + D^-1/2(A+I)D^-1/2 hW1)
    for (int o = t; o < NPGC * F1; o += TPB) {
        const int n = o / F1, f = o - n * F1;
        const float dn = s.dinv[n];
        float a = b1[f] + dn * dn * s.big[n * F1 + f];
        const int e0 = s.off[n], e1 = s.off[n + 1];
        for (int j = e0; j < e1; ++j) a += s.enrm[j] * s.big[s.erow[j] * F1 + f];
        s.u.h1[n * 51 + f] = fmaxf(a, 0.f);
    }
    __syncthreads();

    // P5: pool1 scores, 4 lanes per row
    {
        const int n = t >> 2, q = t & 3;
        const int f0 = q * 13, len = (q == 3) ? 11 : 13;
        float a = 0.f, ss = 0.f;
        for (int j = 0; j < len; ++j) {
            const int f = f0 + j;
            const float w = pw1[f];
            ss += w * w;
            a += s.u.h1[n * 51 + f] * w;
        }
        a  += __shfl_xor(a, 1);  a  += __shfl_xor(a, 2);
        ss += __shfl_xor(ss, 1); ss += __shfl_xor(ss, 2);
        if (q == 0) s.score[n] = tanhf(a / sqrtf(ss));
    }
    __syncthreads();

    // P6: stable descending rank (== jax.lax.top_k)
    if (t < NPGC) {
        const float sc = s.score[t]; int r = 0;
        for (int m = 0; m < NPGC; ++m) {
            const float sm = s.score[m];
            r += (sm > sc) || (sm == sc && m < t);
        }
        s.map[t] = (r < K1C) ? r : -1;
        if (r < K1C) s.inv[r] = t;
    }
    __syncthreads();

    // P7: remap edges
    if (t < EPGC) {
        const int rl = s.map[s.rowm[t]], cl = s.map[s.colm[t]];
        const bool keep = (rl >= 0) && (cl >= 0);
        s.rowm[t] = rl;
        s.colm[t] = keep ? cl : -1;
    }
    __syncthreads();

    // P8: indegree2 + dinv2 + scan
    if (t < K1C) {
        int c = 0;
        for (int e = 0; e < EPGC; ++e) c += (s.colm[e] == t);
        s.dinv[t] = rsqrtf(1.0f + (float)c);
        int sc_ = c;
        #pragma unroll
        for (int d = 1; d < 64; d <<= 1) {
            int y = __shfl_up(sc_, d, 64);
            if (t >= d) sc_ += y;
        }
        s.off[t + 1] = sc_;
        if (t == 0) s.off[0] = 0;
    }
    __syncthreads();

    // P9: CSR2 fill
    if (t < EPGC) {
        const int c_ = s.colm[t];
        if (c_ >= 0) {
            const int r_ = s.rowm[t];
            const float nm = s.dinv[r_] * s.dinv[c_];
            int k = 0;
            for (int e = 0; e < t; ++e) k += (s.colm[e] == c_);
            const int slot = s.off[c_] + k;
            s.erow[slot] = r_;
            s.enrm[slot] = nm;
        }
    }
    __syncthreads();

    // P10: hW2 = (h1[inv]*score) @ W2, register-blocked 6 rows x 4 cols (250 threads)
    if (t < 250) {
        const int fb = t % 25, nb = t / 25;
        const int f0 = fb * 4;
        int   ivr[6]; float scr[6];
        #pragma unroll
        for (int r = 0; r < 6; ++r) {
            const int n = nb + 10 * r;
            const bool val = (n < K1C);
            ivr[r] = val ? s.inv[n] : 0;
            scr[r] = val ? s.score[ivr[r]] : 0.f;
        }
        float acc[6][4];
        #pragma unroll
        for (int r = 0; r < 6; ++r)
            #pragma unroll
            for (int q = 0; q < 4; ++q) acc[r][q] = 0.f;
        const float4* w2v = (const float4*)w2;
        for (int i = 0; i < F1; ++i) {
            const float4 w = w2v[i * 25 + fb];
            #pragma unroll
            for (int r = 0; r < 6; ++r) {
                const float h = s.u.h1[ivr[r] * 51 + i] * scr[r];  // pre-scale: matches h1p order
                acc[r][0] += h * w.x;
                acc[r][1] += h * w.y;
                acc[r][2] += h * w.z;
                acc[r][3] += h * w.w;
            }
        }
        #pragma unroll
        for (int r = 0; r < 6; ++r) {
            const int n = nb + 10 * r;
            if (n < K1C) {
                #pragma unroll
                for (int q = 0; q < 4; ++q) s.big[n * 101 + f0 + q] = acc[r][q];
            }
        }
    }
    __syncthreads();

    // P11: pool2 scores (h2 recomputed on the fly), 4 lanes per row
    if (t < 4 * K1C) {
        const int n = t >> 2, q = t & 3;
        const float dn = s.dinv[n], dn2 = dn * dn;
        const int e0 = s.off[n], e1 = s.off[n + 1];
        float a = 0.f, ss = 0.f;
        for (int j = 0; j < 25; ++j) {
            const int f = q * 25 + j;
            const float w = pw2[f];
            ss += w * w;
            float v = cb2[f] + dn2 * s.big[n * 101 + f];
            for (int e = e0; e < e1; ++e) v += s.enrm[e] * s.big[s.erow[e] * 101 + f];
            a += fmaxf(v, 0.f) * w;
        }
        a  += __shfl_xor(a, 1);  a  += __shfl_xor(a, 2);
        ss += __shfl_xor(ss, 1); ss += __shfl_xor(ss, 2);
        if (q == 0) s.score2[n] = tanhf(a / sqrtf(ss));
    }
    __syncthreads();

    // P12: rank2
    if (t < K1C) {
        const float sc = s.score2[t]; int r = 0;
        for (int m = 0; m < K1C; ++m) {
            const float sm = s.score2[m];
            r += (sm > sc) || (sm == sc && m < t);
        }
        if (r < K2C) s.inv2[r] = t;
    }
    __syncthreads();

    // P13a: readout partials over two row-halves (200 threads)
    if (t < 200) {
        const int f = t % 100, hh = t / 100;
        float mx = -INFINITY, sm = 0.f;
        for (int r = hh * 21; r < hh * 21 + 21; ++r) {
            const int n = s.inv2[r];
            const float dn = s.dinv[n];
            float v = cb2[f] + dn * dn * s.big[n * 101 + f];
            const int e0 = s.off[n], e1 = s.off[n + 1];
            for (int e = e0; e < e1; ++e) v += s.enrm[e] * s.big[s.erow[e] * 101 + f];
            const float y = fmaxf(v, 0.f) * s.score2[n];
            mx = fmaxf(mx, y);
            sm += y;
        }
        s.u.rd[hh * 100 + f]       = mx;
        s.u.rd[200 + hh * 100 + f] = sm;
    }
    __syncthreads();

    // P13b: combine + write pooled
    if (t < 100) {
        float* pd = ws_pooled + (size_t)g * 200;
        pd[t]       = fmaxf(s.u.rd[t], s.u.rd[100 + t]);
        pd[100 + t] = (s.u.rd[200 + t] + s.u.rd[300 + t]) * (1.0f / (float)K2C);
    }
}

// ---------------- head kernel: 8 graphs/block, register-blocked j-major ----------------
#define GPB 8
struct HS {
    union {
        float sp[GPB * 201];
        struct { float d1[GPB * 100]; float d2[GPB * 201]; } b;
    } u;
    float le[GPB * 201];
    float muv[GPB * 50];
    int   sls[GPB];
};

__global__ __launch_bounds__(TPB, 4)
void molgen_head(const float* __restrict__ ws_pooled,
                 const int* __restrict__ smile_len,
                 const float* __restrict__ emb,
                 const float* __restrict__ mean_w,   const float* __restrict__ mean_b,
                 const float* __restrict__ logvar_w, const float* __restrict__ logvar_b,
                 const float* __restrict__ dec1_w, const float* __restrict__ dec1_b,
                 const float* __restrict__ dec2_w, const float* __restrict__ dec2_b,
                 const float* __restrict__ out_w,  const float* __restrict__ out_b,
                 float* __restrict__ out, int B)
{
    __shared__ HS h;
    const int t  = threadIdx.x;
    const int g0 = blockIdx.x * GPB;

    if (t < GPB) h.sls[t] = (g0 + t < B) ? smile_len[g0 + t] : 0;
    __syncthreads();
    for (int o = t; o < GPB * 200; o += TPB) {
        const int gg = o / 200, f = o - gg * 200;
        if (g0 + gg < B) {
            h.u.sp[gg * 201 + f] = ws_pooled[(size_t)(g0 + gg) * 200 + f];
            h.le[gg * 201 + f]   = fmaxf(emb[(size_t)h.sls[gg] * 200 + f], 0.f);
        }
    }
    __syncthreads();

    // mu & logvar: j = t%50, 2 graphs per thread
    if (t < 200) {
        const int j = t % 50, gq = t / 50;
        float am[2] = {mean_b[j], mean_b[j]};
        float al[2] = {logvar_b[j], logvar_b[j]};
        for (int i = 0; i < 200; ++i) {
            const float wm = mean_w[i * 50 + j];
            const float wl = logvar_w[i * 50 + j];
            #pragma unroll
            for (int k = 0; k < 2; ++k) {
                const float p = h.u.sp[(gq * 2 + k) * 201 + i];
                am[k] += p * wm;
                al[k] += p * wl;
            }
        }
        #pragma unroll
        for (int k = 0; k < 2; ++k) {
            const int gg = gq * 2 + k;
            if (g0 + gg < B) {
                const float m = fmaxf(am[k], 0.f);
                h.muv[gg * 50 + j] = m;
                out[(size_t)B * 200 + (size_t)(g0 + gg) * 50 + j] = m;
                out[(size_t)B * 250 + (size_t)(g0 + gg) * 50 + j] = fmaxf(al[k], 0.f);
            }
        }
    }
    __syncthreads();   // sp dead; d1 aliases it

    // d1 = relu([mu, lemb] @ dec1_w + b): j = t%100, 4 graphs per thread
    if (t < 200) {
        const int j = t % 100, gh = t / 100;
        float a[4];
        #pragma unroll
        for (int k = 0; k < 4; ++k) a[k] = dec1_b[j];
        for (int i = 0; i < 50; ++i) {
            const float w = dec1_w[i * 100 + j];
            #pragma unroll
            for (int k = 0; k < 4; ++k) a[k] += h.muv[(gh * 4 + k) * 50 + i] * w;
        }
        for (int i = 0; i < 200; ++i) {
            const float w = dec1_w[(50 + i) * 100 + j];
            #pragma unroll
            for (int k = 0; k < 4; ++k) a[k] += h.le[(gh * 4 + k) * 201 + i] * w;
        }
        #pragma unroll
        for (int k = 0; k < 4; ++k) h.u.b.d1[(gh * 4 + k) * 100 + j] = fmaxf(a[k], 0.f);
    }
    __syncthreads();

    // d2 = relu(d1 @ dec2_w + b) + lemb: j = t, all 8 graphs
    if (t < 200) {
        const int j = t;
        float a[GPB];
        #pragma unroll
        for (int k = 0; k < GPB; ++k) a[k] = dec2_b[j];
        for (int i = 0; i < 100; ++i) {
            const float w = dec2_w[i * 200 + j];
            #pragma unroll
            for (int k = 0; k < GPB; ++k) a[k] += h.u.b.d1[k * 100 + i] * w;
        }
        #pragma unroll
        for (int k = 0; k < GPB; ++k)
            h.u.b.d2[k * 201 + j] = fmaxf(a[k], 0.f) + h.le[k * 201 + j];
    }
    __syncthreads();

    // out = relu(d2 @ out_w + b)
    if (t < 200) {
        const int j = t;
        float a[GPB];
        #pragma unroll
        for (int k = 0; k < GPB; ++k) a[k] = out_b[j];
        for (int i = 0; i < 200; ++i) {
            const float w = out_w[i * 200 + j];
            #pragma unroll
            for (int k = 0; k < GPB; ++k) a[k] += h.u.b.d2[k * 201 + i] * w;
        }
        #pragma unroll
        for (int k = 0; k < GPB; ++k)
            if (g0 + k < B) out[(size_t)(g0 + k) * 200 + j] = fmaxf(a[k], 0.f);
    }
}

extern "C" void kernel_launch(void* const* d_in, const int* in_sizes, int n_in,
                              void* d_out, int out_size, void* d_ws, size_t ws_size,
                              hipStream_t stream) {
    const float* x        = (const float*)d_in[0];
    const int*   ei       = (const int*)d_in[1];
    const int*   slen     = (const int*)d_in[3];
    const float* w1       = (const float*)d_in[4];
    const float* b1       = (const float*)d_in[5];
    const float* pw1      = (const float*)d_in[6];
    const float* w2       = (const float*)d_in[7];
    const float* b2       = (const float*)d_in[8];
    const float* pw2      = (const float*)d_in[9];
    const float* mean_w   = (const float*)d_in[10];
    const float* mean_b   = (const float*)d_in[11];
    const float* logvar_w = (const float*)d_in[12];
    const float* logvar_b = (const float*)d_in[13];
    const float* emb      = (const float*)d_in[14];
    const float* dec1_w   = (const float*)d_in[15];
    const float* dec1_b   = (const float*)d_in[16];
    const float* dec2_w   = (const float*)d_in[17];
    const float* dec2_b   = (const float*)d_in[18];
    const float* out_w    = (const float*)d_in[19];
    const float* out_b    = (const float*)d_in[20];

    const int B = in_sizes[3];
    const int E = in_sizes[1] / 2;

    float* pooled = (float*)d_ws;   // [B][200] fp32

    molgen_graph<<<B, TPB, 0, stream>>>(x, ei, w1, b1, pw1, w2, b2, pw2, pooled, E);
    molgen_head<<<(B + GPB - 1) / GPB, TPB, 0, stream>>>(pooled, slen, emb,
        mean_w, mean_b, logvar_w, logvar_b, dec1_w, dec1_b, dec2_w, dec2_b,
        out_w, out_b, (float*)d_out, B);
}